// Round 1
// baseline (605.146 us; speedup 1.0000x reference)
//
#include <hip/hip_runtime.h>

#define N_NODES 100000
#define N_EDGES 1600000
#define N_PAIRS 1000000

// ---------------------------------------------------------------------------
// Kernel 1: degree count (float, exact up to 2^24 >> max degree)
// ---------------------------------------------------------------------------
__global__ void degree_kernel(const int* __restrict__ dst, float* __restrict__ cnt) {
    int e = blockIdx.x * blockDim.x + threadIdx.x;
    if (e < N_EDGES) atomicAdd(&cnt[dst[e]], 1.0f);
}

// ---------------------------------------------------------------------------
// Kernel 2: scatter-add of feature rows. 32 lanes per edge (one per channel):
// lanes 0..31 read one contiguous 128B row of x (coalesced) and atomically
// add into the dst row.
// ---------------------------------------------------------------------------
__global__ void scatter_kernel(const float* __restrict__ feat,
                               const int* __restrict__ src,
                               const int* __restrict__ dst,
                               float* __restrict__ agg) {
    long long gid = (long long)blockIdx.x * blockDim.x + threadIdx.x;
    int e = (int)(gid >> 5);
    int c = (int)(gid & 31);
    if (e >= N_EDGES) return;
    int s = src[e];
    int d = dst[e];
    atomicAdd(&agg[(long long)d * 32 + c], feat[(long long)s * 32 + c]);
}

// ---------------------------------------------------------------------------
// Kernel 3: fused mean-normalize + dual matvec + bias (+ReLU).
// out[n,:] = act( (agg[n,:]/max(cnt,1)) @ Wl + b + xin[n,:] @ Wr )
// One thread per node; Wl/Wr/b staged in LDS (wave-uniform broadcast reads,
// float4-vectorized: 512 ds_read_b128 instead of 2048 scalar reads).
// out may alias agg (each thread reads only its own row before writing it).
// ---------------------------------------------------------------------------
template <bool RELU>
__global__ void linear_kernel(const float* __restrict__ agg,
                              const float* __restrict__ cnt,
                              const float* __restrict__ xin,
                              const float* __restrict__ Wl,
                              const float* __restrict__ Wr,
                              const float* __restrict__ b,
                              float* __restrict__ out) {
    __shared__ float sWl[32 * 32];
    __shared__ float sWr[32 * 32];
    __shared__ float sb[32];
    for (int i = threadIdx.x; i < 1024; i += blockDim.x) {
        sWl[i] = Wl[i];
        sWr[i] = Wr[i];
    }
    if (threadIdx.x < 32) sb[threadIdx.x] = b[threadIdx.x];
    __syncthreads();

    int n = blockIdx.x * blockDim.x + threadIdx.x;
    if (n >= N_NODES) return;

    float inv = 1.0f / fmaxf(cnt[n], 1.0f);

    float a[32], xr[32];
    const float4* ap = (const float4*)(agg + (long long)n * 32);
    const float4* xp = (const float4*)(xin + (long long)n * 32);
#pragma unroll
    for (int q = 0; q < 8; q++) {
        float4 v = ap[q];
        a[4 * q + 0] = v.x * inv; a[4 * q + 1] = v.y * inv;
        a[4 * q + 2] = v.z * inv; a[4 * q + 3] = v.w * inv;
        float4 u = xp[q];
        xr[4 * q + 0] = u.x; xr[4 * q + 1] = u.y;
        xr[4 * q + 2] = u.z; xr[4 * q + 3] = u.w;
    }

    float o[32];
#pragma unroll
    for (int j = 0; j < 32; j++) o[j] = sb[j];

    // i-outer, j-inner: W rows are contiguous -> float4 LDS reads (broadcast).
#pragma unroll
    for (int i = 0; i < 32; i++) {
        float ai = a[i];
        float xi = xr[i];
        const float4* wlp = (const float4*)(sWl + i * 32);
        const float4* wrp = (const float4*)(sWr + i * 32);
#pragma unroll
        for (int q = 0; q < 8; q++) {
            float4 wl = wlp[q];
            float4 wr = wrp[q];
            o[4 * q + 0] += ai * wl.x + xi * wr.x;
            o[4 * q + 1] += ai * wl.y + xi * wr.y;
            o[4 * q + 2] += ai * wl.z + xi * wr.z;
            o[4 * q + 3] += ai * wl.w + xi * wr.w;
        }
    }

    float4* op = (float4*)(out + (long long)n * 32);
#pragma unroll
    for (int q = 0; q < 8; q++) {
        float4 v;
        if (RELU) {
            v = make_float4(fmaxf(o[4 * q + 0], 0.f), fmaxf(o[4 * q + 1], 0.f),
                            fmaxf(o[4 * q + 2], 0.f), fmaxf(o[4 * q + 3], 0.f));
        } else {
            v = make_float4(o[4 * q + 0], o[4 * q + 1], o[4 * q + 2], o[4 * q + 3]);
        }
        op[q] = v;
    }
}

// ---------------------------------------------------------------------------
// Kernel 4: pair scoring. 8 lanes per pair, each lane loads a float4 of each
// endpoint row (128B per row, coalesced within the 8-lane group), dot, then
// shfl-reduce over the 8 lanes.
// ---------------------------------------------------------------------------
__global__ void pair_kernel(const float* __restrict__ z,
                            const int* __restrict__ pairs,
                            float* __restrict__ out) {
    long long gid = (long long)blockIdx.x * blockDim.x + threadIdx.x;
    int p = (int)(gid >> 3);
    int l = (int)(gid & 7);
    if (p >= N_PAIRS) return;
    int a = pairs[2 * p];
    int b = pairs[2 * p + 1];
    float4 va = *(const float4*)(z + (long long)a * 32 + l * 4);
    float4 vb = *(const float4*)(z + (long long)b * 32 + l * 4);
    float dot = va.x * vb.x + va.y * vb.y + va.z * vb.z + va.w * vb.w;
    dot += __shfl_down(dot, 4, 8);
    dot += __shfl_down(dot, 2, 8);
    dot += __shfl_down(dot, 1, 8);
    if (l == 0) out[p] = dot;
}

// ---------------------------------------------------------------------------
extern "C" void kernel_launch(void* const* d_in, const int* in_sizes, int n_in,
                              void* d_out, int out_size, void* d_ws, size_t ws_size,
                              hipStream_t stream) {
    const float* x    = (const float*)d_in[0];
    const int*   ei   = (const int*)d_in[1];   // [2, E] row-major (int32: JAX x64 disabled)
    const int*   prs  = (const int*)d_in[2];   // [P, 2] row-major
    const float* Wl1  = (const float*)d_in[3];
    const float* Wr1  = (const float*)d_in[4];
    const float* b1   = (const float*)d_in[5];
    const float* Wl2  = (const float*)d_in[6];
    const float* Wr2  = (const float*)d_in[7];
    const float* b2   = (const float*)d_in[8];
    float* out = (float*)d_out;

    const int* src = ei;
    const int* dst = ei + N_EDGES;

    // Workspace layout: agg [N*32] | cnt [N] | h [N*32].  z aliases agg.
    float* agg = (float*)d_ws;
    float* cnt = agg + (size_t)N_NODES * 32;
    float* h   = cnt + N_NODES;
    float* z   = agg;  // safe alias: linear_kernel is row-local read-then-write

    // Zero agg+cnt in one shot (they are adjacent).
    hipMemsetAsync(agg, 0, sizeof(float) * ((size_t)N_NODES * 32 + N_NODES), stream);

    const int BT = 256;
    int degree_blocks  = (N_EDGES + BT - 1) / BT;
    int scatter_blocks = (int)(((long long)N_EDGES * 32 + BT - 1) / BT);
    int linear_blocks  = (N_NODES + BT - 1) / BT;
    int pair_blocks    = (int)(((long long)N_PAIRS * 8 + BT - 1) / BT);

    degree_kernel<<<degree_blocks, BT, 0, stream>>>(dst, cnt);

    // ---- layer 1 ----
    scatter_kernel<<<scatter_blocks, BT, 0, stream>>>(x, src, dst, agg);
    linear_kernel<true><<<linear_blocks, BT, 0, stream>>>(agg, cnt, x, Wl1, Wr1, b1, h);

    // ---- layer 2 ----
    hipMemsetAsync(agg, 0, sizeof(float) * (size_t)N_NODES * 32, stream);
    scatter_kernel<<<scatter_blocks, BT, 0, stream>>>(h, src, dst, agg);
    linear_kernel<false><<<linear_blocks, BT, 0, stream>>>(agg, cnt, h, Wl2, Wr2, b2, z);

    // ---- pair scoring ----
    pair_kernel<<<pair_blocks, BT, 0, stream>>>(z, prs, out);
}

// Round 2
// 456.556 us; speedup vs baseline: 1.3255x; 1.3255x over previous
//
#include <hip/hip_runtime.h>

#define N_NODES 100000
#define N_EDGES 1600000
#define N_PAIRS 1000000
#define SCAN_CHUNK 1024
#define NB_SCAN ((N_NODES + SCAN_CHUNK - 1) / SCAN_CHUNK)  // 98

// ---------------------------------------------------------------------------
// CSR build step 1: in-degree histogram (int atomics, ~1.6M ops).
// ---------------------------------------------------------------------------
__global__ void degree_kernel(const int* __restrict__ dst, int* __restrict__ deg) {
    int e = blockIdx.x * blockDim.x + threadIdx.x;
    if (e < N_EDGES) atomicAdd(&deg[dst[e]], 1);
}

// ---------------------------------------------------------------------------
// CSR build step 2a: per-block inclusive scan of deg (1024 elems/block).
// ---------------------------------------------------------------------------
__global__ void scan1_kernel(const int* __restrict__ deg,
                             int* __restrict__ incl,
                             int* __restrict__ bsum) {
    __shared__ int part[256];
    int t = threadIdx.x;
    int idx = blockIdx.x * SCAN_CHUNK + t * 4;
    int4 v = make_int4(0, 0, 0, 0);
    if (idx + 3 < N_NODES) {
        v = *(const int4*)(deg + idx);
    } else {
        if (idx + 0 < N_NODES) v.x = deg[idx + 0];
        if (idx + 1 < N_NODES) v.y = deg[idx + 1];
        if (idx + 2 < N_NODES) v.z = deg[idx + 2];
        if (idx + 3 < N_NODES) v.w = deg[idx + 3];
    }
    int s0 = v.x, s1 = s0 + v.y, s2 = s1 + v.z, s3 = s2 + v.w;
    part[t] = s3;
    __syncthreads();
    for (int off = 1; off < 256; off <<= 1) {
        int val = (t >= off) ? part[t - off] : 0;
        __syncthreads();
        part[t] += val;
        __syncthreads();
    }
    int excl = (t > 0) ? part[t - 1] : 0;
    if (idx + 0 < N_NODES) incl[idx + 0] = excl + s0;
    if (idx + 1 < N_NODES) incl[idx + 1] = excl + s1;
    if (idx + 2 < N_NODES) incl[idx + 2] = excl + s2;
    if (idx + 3 < N_NODES) incl[idx + 3] = excl + s3;
    if (t == 255) bsum[blockIdx.x] = part[255];
}

// ---------------------------------------------------------------------------
// CSR build step 2b: exclusive scan of the 98 block sums (serial, tiny).
// ---------------------------------------------------------------------------
__global__ void scan2_kernel(int* __restrict__ bsum, int* __restrict__ offsets) {
    if (threadIdx.x == 0 && blockIdx.x == 0) {
        int run = 0;
        for (int i = 0; i < NB_SCAN; i++) {
            int t = bsum[i];
            bsum[i] = run;
            run += t;
        }
        offsets[N_NODES] = run;  // == N_EDGES
    }
}

// ---------------------------------------------------------------------------
// CSR build step 2c: finalize exclusive offsets; duplicate into cursor.
// ---------------------------------------------------------------------------
__global__ void scan3_kernel(const int* __restrict__ incl,
                             const int* __restrict__ deg,
                             const int* __restrict__ bsum,
                             int* __restrict__ offsets,
                             int* __restrict__ cursor) {
    int i = blockIdx.x * blockDim.x + threadIdx.x;
    if (i < N_NODES) {
        int off = incl[i] - deg[i] + bsum[i / SCAN_CHUNK];
        offsets[i] = off;
        cursor[i] = off;
    }
}

// ---------------------------------------------------------------------------
// CSR build step 3: scatter edge srcs into per-dst contiguous ranges.
// ---------------------------------------------------------------------------
__global__ void fill_kernel(const int* __restrict__ src,
                            const int* __restrict__ dst,
                            int* __restrict__ cursor,
                            int* __restrict__ csr) {
    int e = blockIdx.x * blockDim.x + threadIdx.x;
    if (e < N_EDGES) {
        int d = dst[e];
        int pos = atomicAdd(&cursor[d], 1);
        csr[pos] = src[e];
    }
}

// ---------------------------------------------------------------------------
// Fused pull-aggregate + mean + dual matvec + bias (+ReLU).
// 32 lanes per node (one per channel). Gather loop: coalesced 128B row reads,
// 4-way unrolled for memory-level parallelism. No atomics, single write.
// out[n,:] = act( mean_{s in N(n)} feat[s,:] @ Wl + b + feat[n,:] @ Wr )
// ---------------------------------------------------------------------------
template <bool RELU>
__global__ void agg_linear_kernel(const float* __restrict__ feat,
                                  const int* __restrict__ csr,
                                  const int* __restrict__ offs,
                                  const float* __restrict__ Wl,
                                  const float* __restrict__ Wr,
                                  const float* __restrict__ b,
                                  float* __restrict__ out) {
    __shared__ float sWl[1024], sWr[1024], sb[32];
    for (int i = threadIdx.x; i < 1024; i += blockDim.x) {
        sWl[i] = Wl[i];
        sWr[i] = Wr[i];
    }
    if (threadIdx.x < 32) sb[threadIdx.x] = b[threadIdx.x];
    __syncthreads();

    int g = threadIdx.x >> 5;   // node group within block (0..7)
    int c = threadIdx.x & 31;   // channel
    int n = blockIdx.x * 8 + g;
    if (n >= N_NODES) return;

    int beg = offs[n], end = offs[n + 1];
    float a0 = 0.f, a1 = 0.f, a2 = 0.f, a3 = 0.f;
    int j = beg;
    for (; j + 3 < end; j += 4) {
        int s0 = csr[j + 0], s1 = csr[j + 1], s2 = csr[j + 2], s3 = csr[j + 3];
        a0 += feat[s0 * 32 + c];
        a1 += feat[s1 * 32 + c];
        a2 += feat[s2 * 32 + c];
        a3 += feat[s3 * 32 + c];
    }
    for (; j < end; j++) a0 += feat[csr[j] * 32 + c];
    float inv = 1.0f / (float)max(end - beg, 1);
    float acc = ((a0 + a1) + (a2 + a3)) * inv;  // mean-aggregated channel c
    float xr = feat[(long long)n * 32 + c];     // root channel c

    float o = sb[c];
#pragma unroll
    for (int i = 0; i < 32; i++) {
        float ai = __shfl(acc, i, 32);  // agg[i] broadcast within 32-group
        float xi = __shfl(xr, i, 32);   // root[i]
        o += ai * sWl[i * 32 + c] + xi * sWr[i * 32 + c];
    }
    out[(long long)n * 32 + c] = RELU ? fmaxf(o, 0.f) : o;
}

// ---------------------------------------------------------------------------
// Pair scoring: 8 lanes per pair, float4 per lane, shfl-reduce.
// ---------------------------------------------------------------------------
__global__ void pair_kernel(const float* __restrict__ z,
                            const int* __restrict__ pairs,
                            float* __restrict__ out) {
    long long gid = (long long)blockIdx.x * blockDim.x + threadIdx.x;
    int p = (int)(gid >> 3);
    int l = (int)(gid & 7);
    if (p >= N_PAIRS) return;
    int a = pairs[2 * p];
    int b = pairs[2 * p + 1];
    float4 va = *(const float4*)(z + (long long)a * 32 + l * 4);
    float4 vb = *(const float4*)(z + (long long)b * 32 + l * 4);
    float dot = va.x * vb.x + va.y * vb.y + va.z * vb.z + va.w * vb.w;
    dot += __shfl_down(dot, 4, 8);
    dot += __shfl_down(dot, 2, 8);
    dot += __shfl_down(dot, 1, 8);
    if (l == 0) out[p] = dot;
}

// ---------------------------------------------------------------------------
extern "C" void kernel_launch(void* const* d_in, const int* in_sizes, int n_in,
                              void* d_out, int out_size, void* d_ws, size_t ws_size,
                              hipStream_t stream) {
    const float* x   = (const float*)d_in[0];
    const int*   ei  = (const int*)d_in[1];   // [2, E] row-major
    const int*   prs = (const int*)d_in[2];   // [P, 2] row-major
    const float* Wl1 = (const float*)d_in[3];
    const float* Wr1 = (const float*)d_in[4];
    const float* b1  = (const float*)d_in[5];
    const float* Wl2 = (const float*)d_in[6];
    const float* Wr2 = (const float*)d_in[7];
    const float* b2  = (const float*)d_in[8];
    float* out = (float*)d_out;

    const int* src = ei;
    const int* dst = ei + N_EDGES;

    // Workspace layout (16B-aligned blocks first):
    // h [N*32 f] | z [N*32 f] | csr [E i] | deg [N i] | incl [N i]
    // | offsets [N+1 i] | cursor [N i] | bsum [128 i]   -> ~33.6 MB
    float* h = (float*)d_ws;
    float* z = h + (size_t)N_NODES * 32;
    int* csr     = (int*)(z + (size_t)N_NODES * 32);
    int* deg     = csr + N_EDGES;
    int* incl    = deg + N_NODES;
    int* offsets = incl + N_NODES;
    int* cursor  = offsets + (N_NODES + 1);
    int* bsum    = cursor + N_NODES;

    const int BT = 256;
    int edge_blocks = (N_EDGES + BT - 1) / BT;
    int node_blocks = (N_NODES + BT - 1) / BT;
    int agg_blocks  = (N_NODES + 7) / 8;
    int pair_blocks = (int)(((long long)N_PAIRS * 8 + BT - 1) / BT);

    // ---- CSR build (once, shared by both layers) ----
    hipMemsetAsync(deg, 0, sizeof(int) * N_NODES, stream);
    degree_kernel<<<edge_blocks, BT, 0, stream>>>(dst, deg);
    scan1_kernel<<<NB_SCAN, BT, 0, stream>>>(deg, incl, bsum);
    scan2_kernel<<<1, 64, 0, stream>>>(bsum, offsets);
    scan3_kernel<<<node_blocks, BT, 0, stream>>>(incl, deg, bsum, offsets, cursor);
    fill_kernel<<<edge_blocks, BT, 0, stream>>>(src, dst, cursor, csr);

    // ---- layer 1: x -> h ----
    agg_linear_kernel<true><<<agg_blocks, BT, 0, stream>>>(x, csr, offsets, Wl1, Wr1, b1, h);
    // ---- layer 2: h -> z ----
    agg_linear_kernel<false><<<agg_blocks, BT, 0, stream>>>(h, csr, offsets, Wl2, Wr2, b2, z);

    // ---- pair scoring ----
    pair_kernel<<<pair_blocks, BT, 0, stream>>>(z, prs, out);
}

// Round 3
// 387.690 us; speedup vs baseline: 1.5609x; 1.1776x over previous
//
#include <hip/hip_runtime.h>

#define N_NODES 100000
#define N_EDGES 1600000
#define N_PAIRS 1000000
#define SCAN_CHUNK 1024
#define NB_SCAN ((N_NODES + SCAN_CHUNK - 1) / SCAN_CHUNK)  // 98
#define BSHIFT 10
#define NBUCKET ((N_NODES + (1 << BSHIFT) - 1) >> BSHIFT)  // 98 buckets of 1024 nodes
#define EPB 2048  // edges per block in bscatter

// ---------------------------------------------------------------------------
// CSR build step 1: in-degree histogram (int atomics).
// ---------------------------------------------------------------------------
__global__ void degree_kernel(const int* __restrict__ dst, int* __restrict__ deg) {
    int e = blockIdx.x * blockDim.x + threadIdx.x;
    if (e < N_EDGES) atomicAdd(&deg[dst[e]], 1);
}

// ---------------------------------------------------------------------------
// CSR build step 2a: per-block inclusive scan of deg (1024 elems/block).
// ---------------------------------------------------------------------------
__global__ void scan1_kernel(const int* __restrict__ deg,
                             int* __restrict__ incl,
                             int* __restrict__ bsum) {
    __shared__ int part[256];
    int t = threadIdx.x;
    int idx = blockIdx.x * SCAN_CHUNK + t * 4;
    int4 v = make_int4(0, 0, 0, 0);
    if (idx + 3 < N_NODES) {
        v = *(const int4*)(deg + idx);
    } else {
        if (idx + 0 < N_NODES) v.x = deg[idx + 0];
        if (idx + 1 < N_NODES) v.y = deg[idx + 1];
        if (idx + 2 < N_NODES) v.z = deg[idx + 2];
        if (idx + 3 < N_NODES) v.w = deg[idx + 3];
    }
    int s0 = v.x, s1 = s0 + v.y, s2 = s1 + v.z, s3 = s2 + v.w;
    part[t] = s3;
    __syncthreads();
    for (int off = 1; off < 256; off <<= 1) {
        int val = (t >= off) ? part[t - off] : 0;
        __syncthreads();
        part[t] += val;
        __syncthreads();
    }
    int excl = (t > 0) ? part[t - 1] : 0;
    if (idx + 0 < N_NODES) incl[idx + 0] = excl + s0;
    if (idx + 1 < N_NODES) incl[idx + 1] = excl + s1;
    if (idx + 2 < N_NODES) incl[idx + 2] = excl + s2;
    if (idx + 3 < N_NODES) incl[idx + 3] = excl + s3;
    if (t == 255) bsum[blockIdx.x] = part[255];
}

// ---------------------------------------------------------------------------
// CSR build step 2b: exclusive scan of the 98 block sums (serial, tiny).
// ---------------------------------------------------------------------------
__global__ void scan2_kernel(int* __restrict__ bsum, int* __restrict__ offsets) {
    if (threadIdx.x == 0 && blockIdx.x == 0) {
        int run = 0;
        for (int i = 0; i < NB_SCAN; i++) {
            int t = bsum[i];
            bsum[i] = run;
            run += t;
        }
        offsets[N_NODES] = run;  // == N_EDGES
    }
}

// ---------------------------------------------------------------------------
// CSR build step 2c: finalize exclusive offsets; seed per-bucket cursors.
// ---------------------------------------------------------------------------
__global__ void scan3_kernel(const int* __restrict__ incl,
                             const int* __restrict__ deg,
                             const int* __restrict__ bsum,
                             int* __restrict__ offsets,
                             int* __restrict__ bcursor) {
    int i = blockIdx.x * blockDim.x + threadIdx.x;
    if (i < N_NODES) {
        int off = incl[i] - deg[i] + bsum[i / SCAN_CHUNK];
        offsets[i] = off;
        if ((i & ((1 << BSHIFT) - 1)) == 0) bcursor[i >> BSHIFT] = off;
    }
}

// ---------------------------------------------------------------------------
// CSR build step 3a: bucket-level multisplit. Each block stages EPB edges in
// LDS, counts per-bucket, claims one contiguous run per bucket with a single
// global atomic, then writes int2{src,dst} runs. Writes are ~170B contiguous
// runs -> lines mostly single-writer -> writeback ~= data size (13MB), not
// 64B per edge.
// ---------------------------------------------------------------------------
__global__ void bscatter_kernel(const int* __restrict__ src,
                                const int* __restrict__ dst,
                                int* __restrict__ bcursor,
                                int2* __restrict__ bed) {
    __shared__ int hist[NBUCKET];
    __shared__ int base[NBUCKET];
    __shared__ int2 stage[EPB];  // 16 KB
    int t = threadIdx.x;
    long long e0 = (long long)blockIdx.x * EPB;
    int cnt = (int)((N_EDGES - e0 < EPB) ? (N_EDGES - e0) : EPB);

    for (int i = t; i < NBUCKET; i += blockDim.x) hist[i] = 0;
    __syncthreads();
    for (int i = t; i < cnt; i += blockDim.x) {
        int s = src[e0 + i];
        int d = dst[e0 + i];
        stage[i] = make_int2(s, d);
        atomicAdd(&hist[d >> BSHIFT], 1);
    }
    __syncthreads();
    for (int i = t; i < NBUCKET; i += blockDim.x) {
        int c = hist[i];
        base[i] = c ? atomicAdd(&bcursor[i], c) : 0;
        hist[i] = 0;  // reuse as rank counter
    }
    __syncthreads();
    for (int i = t; i < cnt; i += blockDim.x) {
        int2 sd = stage[i];
        int b = sd.y >> BSHIFT;
        int r = atomicAdd(&hist[b], 1);
        bed[base[b] + r] = sd;
    }
}

// ---------------------------------------------------------------------------
// CSR build step 3b: fine scatter within each bucket. One block per bucket:
// per-node cursors in LDS (no global atomics), csr writes confined to the
// bucket's contiguous ~65KB region -> full lines assembled in one XCD's L2.
// ---------------------------------------------------------------------------
__global__ void ffill_kernel(const int2* __restrict__ bed,
                             const int* __restrict__ offs,
                             int* __restrict__ csr) {
    __shared__ int cur[1 << BSHIFT];
    int b = blockIdx.x;
    int nbase = b << BSHIFT;
    int t = threadIdx.x;
    for (int i = t; i < (1 << BSHIFT); i += blockDim.x) {
        int n = nbase + i;
        cur[i] = (n < N_NODES) ? offs[n] : 0;
    }
    __syncthreads();
    int nend = nbase + (1 << BSHIFT);
    if (nend > N_NODES) nend = N_NODES;
    int beg = offs[nbase];
    int end = offs[nend];
    for (int i = beg + t; i < end; i += blockDim.x) {
        int2 sd = bed[i];
        int pos = atomicAdd(&cur[sd.y & ((1 << BSHIFT) - 1)], 1);
        csr[pos] = sd.x;
    }
}

// ---------------------------------------------------------------------------
// Fused pull-aggregate + mean + dual matvec + bias (+ReLU).
// 32 lanes per node (one per channel); 8-way unrolled gather for MLP.
// ---------------------------------------------------------------------------
template <bool RELU>
__global__ void agg_linear_kernel(const float* __restrict__ feat,
                                  const int* __restrict__ csr,
                                  const int* __restrict__ offs,
                                  const float* __restrict__ Wl,
                                  const float* __restrict__ Wr,
                                  const float* __restrict__ b,
                                  float* __restrict__ out) {
    __shared__ float sWl[1024], sWr[1024], sb[32];
    for (int i = threadIdx.x; i < 1024; i += blockDim.x) {
        sWl[i] = Wl[i];
        sWr[i] = Wr[i];
    }
    if (threadIdx.x < 32) sb[threadIdx.x] = b[threadIdx.x];
    __syncthreads();

    int g = threadIdx.x >> 5;
    int c = threadIdx.x & 31;
    int n = blockIdx.x * 8 + g;
    if (n >= N_NODES) return;

    const float* fc = feat + c;
    int beg = offs[n], end = offs[n + 1];
    float a0 = 0.f, a1 = 0.f, a2 = 0.f, a3 = 0.f;
    float a4 = 0.f, a5 = 0.f, a6 = 0.f, a7 = 0.f;
    int j = beg;
    for (; j + 7 < end; j += 8) {
        int s0 = csr[j + 0], s1 = csr[j + 1], s2 = csr[j + 2], s3 = csr[j + 3];
        int s4 = csr[j + 4], s5 = csr[j + 5], s6 = csr[j + 6], s7 = csr[j + 7];
        a0 += fc[s0 * 32]; a1 += fc[s1 * 32];
        a2 += fc[s2 * 32]; a3 += fc[s3 * 32];
        a4 += fc[s4 * 32]; a5 += fc[s5 * 32];
        a6 += fc[s6 * 32]; a7 += fc[s7 * 32];
    }
    for (; j < end; j++) a0 += fc[csr[j] * 32];
    float inv = 1.0f / (float)max(end - beg, 1);
    float acc = (((a0 + a1) + (a2 + a3)) + ((a4 + a5) + (a6 + a7))) * inv;
    float xr = fc[n * 32];

    float o = sb[c];
#pragma unroll
    for (int i = 0; i < 32; i++) {
        float ai = __shfl(acc, i, 32);
        float xi = __shfl(xr, i, 32);
        o += ai * sWl[i * 32 + c] + xi * sWr[i * 32 + c];
    }
    out[(long long)n * 32 + c] = RELU ? fmaxf(o, 0.f) : o;
}

// ---------------------------------------------------------------------------
// Pair scoring: 8 lanes per pair, float4 per lane, shfl-reduce.
// ---------------------------------------------------------------------------
__global__ void pair_kernel(const float* __restrict__ z,
                            const int* __restrict__ pairs,
                            float* __restrict__ out) {
    long long gid = (long long)blockIdx.x * blockDim.x + threadIdx.x;
    int p = (int)(gid >> 3);
    int l = (int)(gid & 7);
    if (p >= N_PAIRS) return;
    int a = pairs[2 * p];
    int b = pairs[2 * p + 1];
    float4 va = *(const float4*)(z + (long long)a * 32 + l * 4);
    float4 vb = *(const float4*)(z + (long long)b * 32 + l * 4);
    float dot = va.x * vb.x + va.y * vb.y + va.z * vb.z + va.w * vb.w;
    dot += __shfl_down(dot, 4, 8);
    dot += __shfl_down(dot, 2, 8);
    dot += __shfl_down(dot, 1, 8);
    if (l == 0) out[p] = dot;
}

// ---------------------------------------------------------------------------
extern "C" void kernel_launch(void* const* d_in, const int* in_sizes, int n_in,
                              void* d_out, int out_size, void* d_ws, size_t ws_size,
                              hipStream_t stream) {
    const float* x   = (const float*)d_in[0];
    const int*   ei  = (const int*)d_in[1];   // [2, E] row-major
    const int*   prs = (const int*)d_in[2];   // [P, 2] row-major
    const float* Wl1 = (const float*)d_in[3];
    const float* Wr1 = (const float*)d_in[4];
    const float* b1  = (const float*)d_in[5];
    const float* Wl2 = (const float*)d_in[6];
    const float* Wr2 = (const float*)d_in[7];
    const float* b2  = (const float*)d_in[8];
    float* out = (float*)d_out;

    const int* src = ei;
    const int* dst = ei + N_EDGES;

    // Workspace: h [N*32 f] | z [N*32 f] | csr [E i] | deg [N i] | incl [N i]
    //            | offsets [N+1 i] | bsum [128 i] | bcursor [128 i]
    // bed (int2, E = 12.8MB) aliases z: z is only written in layer 2, after
    // the CSR build has fully consumed bed.
    float* h = (float*)d_ws;
    float* z = h + (size_t)N_NODES * 32;
    int* csr     = (int*)(z + (size_t)N_NODES * 32);
    int* deg     = csr + N_EDGES;
    int* incl    = deg + N_NODES;
    int* offsets = incl + N_NODES;
    int* bsum    = offsets + (N_NODES + 1);
    int* bcursor = bsum + 128;
    int2* bed    = (int2*)z;

    const int BT = 256;
    int edge_blocks = (N_EDGES + BT - 1) / BT;
    int node_blocks = (N_NODES + BT - 1) / BT;
    int bsc_blocks  = (N_EDGES + EPB - 1) / EPB;
    int agg_blocks  = (N_NODES + 7) / 8;
    int pair_blocks = (int)(((long long)N_PAIRS * 8 + BT - 1) / BT);

    // ---- CSR build (once, shared by both layers) ----
    hipMemsetAsync(deg, 0, sizeof(int) * N_NODES, stream);
    degree_kernel<<<edge_blocks, BT, 0, stream>>>(dst, deg);
    scan1_kernel<<<NB_SCAN, BT, 0, stream>>>(deg, incl, bsum);
    scan2_kernel<<<1, 64, 0, stream>>>(bsum, offsets);
    scan3_kernel<<<node_blocks, BT, 0, stream>>>(incl, deg, bsum, offsets, bcursor);
    bscatter_kernel<<<bsc_blocks, BT, 0, stream>>>(src, dst, bcursor, bed);
    ffill_kernel<<<NBUCKET, 512, 0, stream>>>(bed, offsets, csr);

    // ---- layer 1: x -> h ----
    agg_linear_kernel<true><<<agg_blocks, BT, 0, stream>>>(x, csr, offsets, Wl1, Wr1, b1, h);
    // ---- layer 2: h -> z ----  (z overwrites bed, which is now dead)
    agg_linear_kernel<false><<<agg_blocks, BT, 0, stream>>>(h, csr, offsets, Wl2, Wr2, b2, z);

    // ---- pair scoring ----
    pair_kernel<<<pair_blocks, BT, 0, stream>>>(z, prs, out);
}